// Round 1
// baseline (17836.311 us; speedup 1.0000x reference)
//
#include <hip/hip_runtime.h>
#include <hip/hip_bf16.h>

// FF_attention_module: sLSTM scan (T=128) + attention epilogue.
// Round 1: correctness-first. Gate GEMM in fp32 VALU with bf16-rounded
// operands (exact emulation of the round-2 MFMA numerics).

namespace {
constexpr int B_  = 1024;
constexpr int T_  = 128;
constexpr int D_  = 16;
constexpr int N_  = 64;
constexpr int DN_ = 1024;   // D*N
constexpr int K_  = 1040;   // D*(N+1)
constexpr int MB_ = 64;     // batch tile per block
}

__device__ __forceinline__ unsigned short f2bf(float v) {
    unsigned int u = __float_as_uint(v);
    unsigned int r = u + 0x7FFFu + ((u >> 16) & 1u);   // RNE
    return (unsigned short)(r >> 16);
}
__device__ __forceinline__ float bf16r(float v) {
    return __uint_as_float((unsigned int)f2bf(v) << 16);
}
__device__ __forceinline__ float bits2f(unsigned int u) {
    return __uint_as_float(u);
}
__device__ __forceinline__ float tanhf_fast(float x) {
    x = fminf(fmaxf(x, -15.0f), 15.0f);
    float e = __expf(2.0f * x);
    return (e - 1.0f) / (e + 1.0f);
}
__device__ __forceinline__ float sigmoidf_fast(float x) {
    return 1.0f / (1.0f + __expf(-x));
}

// One recurrence step. Grid: (16 batch-tiles, 16 d). Block: 256 threads.
// Block (bt, d) owns outputs (b in [bt*64,bt*64+64), gate cols d*64..d*64+63
// for all three gates), i.e. it computes i,f,o,j and the c/h update for its
// (b-tile, d) slice, plus the online alpha accumulation for that slice.
__global__ __launch_bounds__(256, 1)
void step_kernel(int t,
    const float* __restrict__ x,
    const float* __restrict__ Wi_w, const float* __restrict__ Wi_b,
    const float* __restrict__ Wf_w, const float* __restrict__ Wf_b,
    const float* __restrict__ Wo_w, const float* __restrict__ Wo_b,
    const float* __restrict__ W_j,  const float* __restrict__ U_j,
    const float* __restrict__ b_j,  const float* __restrict__ F_an,
    const float* __restrict__ F_anb,
    const unsigned short* __restrict__ h_in,   // bf16 h (previous step), [B][DN]
    unsigned short* __restrict__ h_out,        // bf16 h (this step)
    float* __restrict__ h_f32,                 // fp32 h, block-private slices
    float* __restrict__ c_st,                  // fp32 c
    float* __restrict__ Se, float* __restrict__ Seh)
{
    const int bt  = blockIdx.x;
    const int d   = blockIdx.y;
    const int b0  = bt * MB_;
    const int tid = threadIdx.x;
    const int tb  = tid >> 4;   // 0..15 -> 4 batch rows each
    const int tn  = tid & 15;   // 0..15 -> 4 cols per gate each

    __shared__ float w_s[64][192];      // weight tile [k][3*64 cols] (bf16-rounded)
    __shared__ float a_s[64][MB_];      // inp tile [k][b] (bf16 values as fp32)
    __shared__ float jh_s[N_][MB_];     // fp32 h slice for j, [n][b]
    __shared__ float wj_s[N_][N_];      // W_j[d], [n][m]
    __shared__ float x_s[D_][MB_];      // x_t tile, [feat][b]
    __shared__ float hn_s[MB_][N_ + 1]; // new h for alpha stage
    __shared__ float u_s[N_], bj_s[N_], fa_s[N_];

    // ---- stage small per-step data ----
    {
        int b = tid >> 2, q = tid & 3;
        float4 xv = *(const float4*)&x[(size_t)(b0 + b) * (T_ * D_) + t * D_ + q * 4];
        x_s[q * 4 + 0][b] = xv.x; x_s[q * 4 + 1][b] = xv.y;
        x_s[q * 4 + 2][b] = xv.z; x_s[q * 4 + 3][b] = xv.w;

        const float* hsrc = &h_f32[(size_t)(b0 + b) * DN_ + d * N_ + q * 16];
        #pragma unroll
        for (int i = 0; i < 16; i += 4) {
            float4 v = *(const float4*)&hsrc[i];
            jh_s[q * 16 + i + 0][b] = v.x; jh_s[q * 16 + i + 1][b] = v.y;
            jh_s[q * 16 + i + 2][b] = v.z; jh_s[q * 16 + i + 3][b] = v.w;
        }
    }
    {
        const float* src = &W_j[(size_t)d * N_ * N_];
        int base = tid * 16;
        #pragma unroll
        for (int i = 0; i < 16; i += 4)
            *(float4*)&(&wj_s[0][0])[base + i] = *(const float4*)&src[base + i];
    }
    if (tid < N_) {
        u_s[tid]  = U_j[d * N_ + tid];
        bj_s[tid] = b_j[d * N_ + tid];
        fa_s[tid] = F_an[d * N_ + tid];
    }
    __syncthreads();

    // ---- phase 1: j = tanh(h @ W_j[d] + x_d*u + b_j), fp32 ----
    float jr[4][4];
    {
        float ja[4][4] = {};
        #pragma unroll 8
        for (int n = 0; n < N_; ++n) {
            float4 wv = *(const float4*)&wj_s[n][tn * 4];
            float4 hv = *(const float4*)&jh_s[n][tb * 4];
            float w4[4] = {wv.x, wv.y, wv.z, wv.w};
            float h4[4] = {hv.x, hv.y, hv.z, hv.w};
            #pragma unroll
            for (int bi = 0; bi < 4; ++bi)
                #pragma unroll
                for (int mi = 0; mi < 4; ++mi)
                    ja[bi][mi] += h4[bi] * w4[mi];
        }
        float4 xd = *(const float4*)&x_s[d][tb * 4];
        float x4[4] = {xd.x, xd.y, xd.z, xd.w};
        #pragma unroll
        for (int bi = 0; bi < 4; ++bi)
            #pragma unroll
            for (int mi = 0; mi < 4; ++mi)
                jr[bi][mi] = tanhf_fast(ja[bi][mi] + x4[bi] * u_s[tn * 4 + mi] + bj_s[tn * 4 + mi]);
    }

    // ---- phase 2: fused 3-gate GEMM, bf16-emulated operands, fp32 accum ----
    float acc[4][12];   // [bi][g*4+mi], g: 0=i 1=f 2=o
    #pragma unroll
    for (int g = 0; g < 3; ++g) {
        const float* Bg = (g == 0) ? Wi_b : (g == 1) ? Wf_b : Wo_b;
        #pragma unroll
        for (int mi = 0; mi < 4; ++mi) {
            float bv = Bg[d * N_ + tn * 4 + mi];
            #pragma unroll
            for (int bi = 0; bi < 4; ++bi) acc[bi][g * 4 + mi] = bv;
        }
    }

    // x-part of inp (k = 0..15)
    for (int idx = tid; idx < 192 * 4; idx += 256) {
        int col = idx % 192, kq = idx / 192;
        int g = col >> 6, row = d * N_ + (col & 63);
        const float* Wg = (g == 0) ? Wi_w : (g == 1) ? Wf_w : Wo_w;
        float4 wv = *(const float4*)&Wg[(size_t)row * K_ + kq * 4];
        w_s[kq * 4 + 0][col] = bf16r(wv.x); w_s[kq * 4 + 1][col] = bf16r(wv.y);
        w_s[kq * 4 + 2][col] = bf16r(wv.z); w_s[kq * 4 + 3][col] = bf16r(wv.w);
    }
    __syncthreads();
    #pragma unroll
    for (int kk = 0; kk < 16; ++kk) {
        float4 av = *(const float4*)&x_s[kk][tb * 4];
        float a4[4] = {bf16r(av.x), bf16r(av.y), bf16r(av.z), bf16r(av.w)};
        float4 w0 = *(const float4*)&w_s[kk][tn * 4];
        float4 w1 = *(const float4*)&w_s[kk][64 + tn * 4];
        float4 w2 = *(const float4*)&w_s[kk][128 + tn * 4];
        float wv[12] = {w0.x, w0.y, w0.z, w0.w, w1.x, w1.y, w1.z, w1.w, w2.x, w2.y, w2.z, w2.w};
        #pragma unroll
        for (int bi = 0; bi < 4; ++bi)
            #pragma unroll
            for (int j = 0; j < 12; ++j)
                acc[bi][j] += a4[bi] * wv[j];
    }

    // h-part of inp (k = 16..1039), 16 chunks of 64
    for (int ch = 0; ch < 16; ++ch) {
        __syncthreads();
        {
            int b = tid >> 2, ks = (tid & 3) * 16;
            const unsigned short* src = h_in + (size_t)(b0 + b) * DN_ + ch * 64 + ks;
            #pragma unroll
            for (int hh = 0; hh < 2; ++hh) {
                uint4 v = *(const uint4*)(src + hh * 8);
                unsigned int u4[4] = {v.x, v.y, v.z, v.w};
                #pragma unroll
                for (int p = 0; p < 4; ++p) {
                    a_s[ks + hh * 8 + p * 2 + 0][b] = bits2f(u4[p] << 16);
                    a_s[ks + hh * 8 + p * 2 + 1][b] = bits2f(u4[p] & 0xFFFF0000u);
                }
            }
        }
        for (int idx = tid; idx < 192 * 16; idx += 256) {
            int col = idx % 192, kq = idx / 192;
            int g = col >> 6, row = d * N_ + (col & 63);
            const float* Wg = (g == 0) ? Wi_w : (g == 1) ? Wf_w : Wo_w;
            float4 wv = *(const float4*)&Wg[(size_t)row * K_ + 16 + ch * 64 + kq * 4];
            w_s[kq * 4 + 0][col] = bf16r(wv.x); w_s[kq * 4 + 1][col] = bf16r(wv.y);
            w_s[kq * 4 + 2][col] = bf16r(wv.z); w_s[kq * 4 + 3][col] = bf16r(wv.w);
        }
        __syncthreads();
        #pragma unroll 8
        for (int kk = 0; kk < 64; ++kk) {
            float4 av = *(const float4*)&a_s[kk][tb * 4];
            float a4[4] = {av.x, av.y, av.z, av.w};
            float4 w0 = *(const float4*)&w_s[kk][tn * 4];
            float4 w1 = *(const float4*)&w_s[kk][64 + tn * 4];
            float4 w2 = *(const float4*)&w_s[kk][128 + tn * 4];
            float wv[12] = {w0.x, w0.y, w0.z, w0.w, w1.x, w1.y, w1.z, w1.w, w2.x, w2.y, w2.z, w2.w};
            #pragma unroll
            for (int bi = 0; bi < 4; ++bi)
                #pragma unroll
                for (int j = 0; j < 12; ++j)
                    acc[bi][j] += a4[bi] * wv[j];
        }
    }

    // ---- phase 3: c/h update ----
    #pragma unroll
    for (int bi = 0; bi < 4; ++bi) {
        int b = tb * 4 + bi;
        size_t gidx = (size_t)(b0 + b) * DN_ + d * N_ + tn * 4;
        float4 cold = *(const float4*)&c_st[gidx];
        float c4[4] = {cold.x, cold.y, cold.z, cold.w};
        float hnv[4];
        #pragma unroll
        for (int mi = 0; mi < 4; ++mi) {
            float iv = sigmoidf_fast(acc[bi][0 + mi]);
            float fv = sigmoidf_fast(acc[bi][4 + mi]);
            float ov = sigmoidf_fast(acc[bi][8 + mi]);
            float cn = c4[mi] * fv + iv * jr[bi][mi];
            float hn = ov * tanhf_fast(cn);
            c4[mi] = cn;
            hnv[mi] = hn;
            hn_s[b][tn * 4 + mi] = hn;
        }
        *(float4*)&c_st[gidx]  = make_float4(c4[0], c4[1], c4[2], c4[3]);
        *(float4*)&h_f32[gidx] = make_float4(hnv[0], hnv[1], hnv[2], hnv[3]);
        ushort4 pk = make_ushort4(f2bf(hnv[0]), f2bf(hnv[1]), f2bf(hnv[2]), f2bf(hnv[3]));
        *(ushort4*)&h_out[gidx] = pk;
    }
    __syncthreads();

    // ---- phase 4: online alpha accumulation ----
    {
        int b = tid >> 2, q = tid & 3;
        float s = 0.0f;
        #pragma unroll
        for (int i = 0; i < 16; ++i) s += hn_s[b][q * 16 + i] * fa_s[q * 16 + i];
        s += __shfl_xor(s, 1);
        s += __shfl_xor(s, 2);
        float e = __expf(tanhf_fast(s + F_anb[d]));
        float* seh = &Seh[((size_t)(b0 + b) * D_ + d) * N_];
        #pragma unroll
        for (int i = 0; i < 16; ++i) {
            int n = q * 16 + i;
            seh[n] += e * hn_s[b][n];
        }
        if (q == 0) Se[(size_t)(b0 + b) * D_ + d] += e;
    }
}

// Epilogue: g_n = Seh/Se; hg=[g_n, h_T]; mu, betas, weighted sum over d.
__global__ __launch_bounds__(64)
void final_kernel(const float* __restrict__ h_f32,
                  const float* __restrict__ Se, const float* __restrict__ Seh,
                  const float* __restrict__ F_bw, const float* __restrict__ F_bb,
                  const float* __restrict__ Phi_w, const float* __restrict__ Phi_b,
                  float* __restrict__ out)
{
    int b = blockIdx.x;
    int tid = threadIdx.x;
    int d = tid >> 2, q = tid & 3;
    float se_inv = 1.0f / Se[(size_t)b * D_ + d];
    float mu = 0.0f, be = 0.0f;
    #pragma unroll
    for (int i = 0; i < 32; ++i) {
        int k = q * 32 + i;
        float hg = (k < 64) ? Seh[((size_t)b * D_ + d) * N_ + k] * se_inv
                            : h_f32[(size_t)b * DN_ + d * N_ + (k - 64)];
        mu += hg * Phi_w[k];
        be += hg * F_bw[k];
    }
    mu += __shfl_xor(mu, 1); mu += __shfl_xor(mu, 2);
    be += __shfl_xor(be, 1); be += __shfl_xor(be, 2);
    float mud = mu + Phi_b[0];
    float br  = __expf(tanhf_fast(be + F_bb[0]));
    float num = br * mud, den = br;
    #pragma unroll
    for (int off = 4; off < 64; off <<= 1) {
        num += __shfl_xor(num, off);
        den += __shfl_xor(den, off);
    }
    if (tid == 0) out[b] = num / den;
}

extern "C" void kernel_launch(void* const* d_in, const int* in_sizes, int n_in,
                              void* d_out, int out_size, void* d_ws, size_t ws_size,
                              hipStream_t stream)
{
    (void)in_sizes; (void)n_in; (void)out_size; (void)ws_size;
    const float* x     = (const float*)d_in[0];
    const float* U_j   = (const float*)d_in[1];
    const float* W_j   = (const float*)d_in[2];
    const float* b_j   = (const float*)d_in[3];
    const float* Wi_w  = (const float*)d_in[4];
    const float* Wi_b  = (const float*)d_in[5];
    const float* Wf_w  = (const float*)d_in[6];
    const float* Wf_b  = (const float*)d_in[7];
    const float* Wo_w  = (const float*)d_in[8];
    const float* Wo_b  = (const float*)d_in[9];
    const float* F_an  = (const float*)d_in[10];
    const float* F_anb = (const float*)d_in[11];
    const float* F_bw  = (const float*)d_in[12];
    const float* F_bb  = (const float*)d_in[13];
    const float* Phi_w = (const float*)d_in[14];
    const float* Phi_b = (const float*)d_in[15];
    float* out = (float*)d_out;

    char* ws = (char*)d_ws;
    unsigned short* hbf[2] = { (unsigned short*)ws,
                               (unsigned short*)(ws + (size_t)2 * 1024 * 1024) };
    float* h_f32 = (float*)(ws + (size_t)4  * 1024 * 1024);
    float* c_st  = (float*)(ws + (size_t)8  * 1024 * 1024);
    float* Seh   = (float*)(ws + (size_t)12 * 1024 * 1024);
    float* Se    = (float*)(ws + (size_t)16 * 1024 * 1024);
    size_t total = (size_t)16 * 1024 * 1024 + (size_t)B_ * D_ * sizeof(float);

    hipMemsetAsync(d_ws, 0, total, stream);

    dim3 grid(16, 16), block(256);
    for (int t = 0; t < T_; ++t) {
        step_kernel<<<grid, block, 0, stream>>>(t, x,
            Wi_w, Wi_b, Wf_w, Wf_b, Wo_w, Wo_b,
            W_j, U_j, b_j, F_an, F_anb,
            hbf[t & 1], hbf[(t + 1) & 1], h_f32, c_st, Se, Seh);
    }
    final_kernel<<<dim3(B_), dim3(64), 0, stream>>>(h_f32, Se, Seh, F_bw, F_bb, Phi_w, Phi_b, out);
}

// Round 2
// 3638.337 us; speedup vs baseline: 4.9023x; 4.9023x over previous
//
#include <hip/hip_runtime.h>
#include <hip/hip_bf16.h>

// FF_attention_module: sLSTM scan (T=128) + attention epilogue.
// Round 2: MFMA gate GEMM + MFMA j-GEMM. Chunked bf16 weight/activation
// layouts staged via global_load_lds (width 16). Double-buffered LDS.

namespace {
constexpr int B_  = 1024;
constexpr int T_  = 128;
constexpr int D_  = 16;
constexpr int N_  = 64;
constexpr int DN_ = 1024;
constexpr int KP_ = 1056;             // padded K (33 chunks of 32)
constexpr int NCH = 33;

// workspace layout (bytes)
constexpr size_t INPBUF   = (size_t)132 * 1024 * 16;      // 2,162,688
constexpr size_t OFF_INP0 = 0;
constexpr size_t OFF_INP1 = INPBUF;
constexpr size_t OFF_C    = 2 * INPBUF;                   // 4,325,376
constexpr size_t OFF_SEH  = OFF_C   + (size_t)B_ * DN_ * 4;   // 8,519,680
constexpr size_t OFF_SE   = OFF_SEH + (size_t)B_ * DN_ * 4;   // 12,713,984
constexpr size_t OFF_HT   = OFF_SE  + (size_t)B_ * D_ * 4;    // 12,779,520
constexpr size_t OFF_W2   = OFF_HT  + (size_t)B_ * DN_ * 4;   // 16,973,824
constexpr size_t OFF_WJ2  = OFF_W2  + (size_t)16 * 33 * 4 * 192 * 8 * 2; // 23,461,888
constexpr size_t ZERO_BYTES = OFF_HT;                     // zero inp/c/Seh/Se
}

typedef __attribute__((ext_vector_type(8))) __bf16 bf8;
typedef __attribute__((ext_vector_type(4))) float  f4;

__device__ __forceinline__ unsigned short f2bf(float v) {
    unsigned int u = __float_as_uint(v);
    unsigned int r = u + 0x7FFFu + ((u >> 16) & 1u);   // RNE
    return (unsigned short)(r >> 16);
}
__device__ __forceinline__ float tanhf_fast(float x) {
    x = fminf(fmaxf(x, -15.0f), 15.0f);
    float e = __expf(2.0f * x);
    return (e - 1.0f) / (e + 1.0f);
}
__device__ __forceinline__ float sigmoidf_fast(float x) {
    return 1.0f / (1.0f + __expf(-x));
}
__device__ __forceinline__ void gl16(const unsigned short* g, unsigned short* l) {
    __builtin_amdgcn_global_load_lds(
        (const __attribute__((address_space(1))) unsigned int*)g,
        (__attribute__((address_space(3))) unsigned int*)l, 16, 0, 0);
}

// ---- prep: convert gate weights fp32 -> bf16 in chunk-exact staging order ----
// W2 flat: (((d*33 + ch)*4 + kgrp)*192 + col)*8 + e ; col = gate*64 + c
__global__ __launch_bounds__(256)
void prep_w2(const float* __restrict__ Wi, const float* __restrict__ Wf,
             const float* __restrict__ Wo, unsigned short* __restrict__ W2)
{
    int idx = blockIdx.x * 256 + threadIdx.x;
    if (idx >= 16 * 33 * 4 * 192 * 8) return;
    int e    = idx & 7;
    int g3   = idx >> 3;
    int col  = g3 % 192;
    int g2   = g3 / 192;
    int kgrp = g2 & 3;
    int g1   = g2 >> 2;
    int ch   = g1 % 33;
    int d    = g1 / 33;
    int k    = ch * 32 + kgrp * 8 + e;
    int gate = col >> 6, c = col & 63;
    float v = 0.0f;
    if (k < 1040) {
        const float* W = (gate == 0) ? Wi : (gate == 1) ? Wf : Wo;
        v = W[(size_t)(d * 64 + c) * 1040 + k];
    }
    W2[idx] = f2bf(v);
}

// Wj2 flat: ((d*8 + kb)*64 + m)*8 + e   (value = W_j[d][n=kb*8+e][m])
// plus x(t=0) into inp buffer 0 (granules 0..1)
__global__ __launch_bounds__(256)
void prep_misc(const float* __restrict__ Wj, const float* __restrict__ x,
               unsigned short* __restrict__ Wj2, unsigned short* __restrict__ inp0)
{
    int idx = blockIdx.x * 256 + threadIdx.x;
    if (idx < 65536) {
        int e  = idx & 7;
        int m  = (idx >> 3) & 63;
        int kb = (idx >> 9) & 7;
        int d  = idx >> 12;
        int n  = kb * 8 + e;
        Wj2[idx] = f2bf(Wj[((size_t)d * 64 + n) * 64 + m]);
    } else if (idx < 65536 + 16384) {
        int i2   = idx - 65536;
        int feat = i2 & 15;
        int b    = i2 >> 4;
        float v  = x[(size_t)b * (T_ * D_) + 0 * D_ + feat];
        inp0[(((size_t)(feat >> 3)) * 1024 + b) * 8 + (feat & 7)] = f2bf(v);
    }
}

// ---- one recurrence step ----
// grid (16 d, 16 bt), 256 threads = 4 waves. Wave w owns gate cols
// {g*64 + w*16 .. +16} (same dn range for i/f/o/j -> lane-local update).
__global__ __launch_bounds__(256, 1)
void step_kernel(int t,
    const float* __restrict__ x,
    const float* __restrict__ U_j, const float* __restrict__ b_j,
    const float* __restrict__ Wi_b, const float* __restrict__ Wf_b,
    const float* __restrict__ Wo_b,
    const float* __restrict__ F_an, const float* __restrict__ F_anb,
    const unsigned short* __restrict__ W2, const unsigned short* __restrict__ Wj2,
    const unsigned short* __restrict__ inp_cur, unsigned short* __restrict__ inp_nxt,
    float* __restrict__ c_st, float* __restrict__ hT,
    float* __restrict__ Se, float* __restrict__ Seh)
{
    const int d   = blockIdx.x;
    const int bt  = blockIdx.y;
    const int b0  = bt * 64;
    const int tid = threadIdx.x;
    const int wv  = tid >> 6;
    const int ln  = tid & 63;
    const int lr  = ln & 15;     // fragment row/col index
    const int lg  = ln >> 4;     // k-group

    __shared__ __align__(16) unsigned short a_s[2][4 * 64 * 8];    // 8 KB
    __shared__ __align__(16) unsigned short w_s[2][4 * 192 * 8];   // 24 KB
    __shared__ __align__(16) unsigned short jh_s[8 * 64 * 8];      // 8 KB
    __shared__ __align__(16) unsigned short wj_s[8 * 64 * 8];      // 8 KB
    __shared__ float hn_s[64][65];                                  // 16.25 KB
    __shared__ float xd_s[64], fa_s[64];

    // ---- initial staging: j inputs + chunk 0 ----
    #pragma unroll
    for (int i = 0; i < 2; ++i) {       // jh: h d-slice, granules 2+8d+kb
        int kb = i * 4 + wv;
        gl16(inp_cur + ((size_t)(2 + 8 * d + kb) * 1024 + b0 + ln) * 8,
             &jh_s[kb * 512]);
    }
    #pragma unroll
    for (int i = 0; i < 2; ++i) {       // Wj2[d]: 512 granules
        int gr = (i * 4 + wv) * 64;
        gl16(Wj2 + (size_t)d * 4096 + (size_t)(gr + ln) * 8, &wj_s[gr * 8]);
    }
    gl16(inp_cur + ((size_t)(0 * 4 + wv) * 1024 + b0 + ln) * 8, &a_s[0][wv * 512]);
    {
        const unsigned short* wsrc = W2 + (size_t)(d * 33 + 0) * 768 * 8;
        #pragma unroll
        for (int i = 0; i < 3; ++i) {
            int gr = (i * 4 + wv) * 64;
            gl16(wsrc + (size_t)(gr + ln) * 8, &w_s[0][gr * 8]);
        }
    }
    if (tid < 64) {
        xd_s[tid] = x[(size_t)(b0 + tid) * (T_ * D_) + t * D_ + d];
        fa_s[tid] = F_an[d * 64 + tid];
    }
    __syncthreads();

    // ---- j-phase: j = tanh(h_d @ W_j[d] + x_d*u + b_j) via MFMA ----
    const f4 fz = {0.f, 0.f, 0.f, 0.f};
    f4 jacc[4] = {fz, fz, fz, fz};
    #pragma unroll
    for (int ks = 0; ks < 2; ++ks) {
        bf8 bw = *(const bf8*)&wj_s[((ks * 4 + lg) * 64 + wv * 16 + lr) * 8];
        #pragma unroll
        for (int mf = 0; mf < 4; ++mf) {
            bf8 ah = *(const bf8*)&jh_s[((ks * 4 + lg) * 64 + mf * 16 + lr) * 8];
            jacc[mf] = __builtin_amdgcn_mfma_f32_16x16x32_bf16(ah, bw, jacc[mf], 0, 0, 0);
        }
    }
    const int coln = wv * 16 + lr;       // dn within d-slice
    float jr[4][4];
    {
        float uc = U_j[d * 64 + coln];
        float bc = b_j[d * 64 + coln];
        #pragma unroll
        for (int mf = 0; mf < 4; ++mf)
            #pragma unroll
            for (int r = 0; r < 4; ++r)
                jr[mf][r] = tanhf_fast(jacc[mf][r] + xd_s[mf * 16 + lg * 4 + r] * uc + bc);
    }

    // ---- main loop: fused 3-gate GEMM over 33 chunks of K=32 ----
    f4 acc[4][3];
    #pragma unroll
    for (int mf = 0; mf < 4; ++mf)
        #pragma unroll
        for (int g = 0; g < 3; ++g) acc[mf][g] = fz;

    int buf = 0;
    for (int ch = 0; ch < NCH; ++ch) {
        if (ch < NCH - 1) {   // prefetch next chunk into buf^1
            gl16(inp_cur + ((size_t)((ch + 1) * 4 + wv) * 1024 + b0 + ln) * 8,
                 &a_s[buf ^ 1][wv * 512]);
            const unsigned short* wsrc = W2 + (size_t)(d * 33 + ch + 1) * 768 * 8;
            #pragma unroll
            for (int i = 0; i < 3; ++i) {
                int gr = (i * 4 + wv) * 64;
                gl16(wsrc + (size_t)(gr + ln) * 8, &w_s[buf ^ 1][gr * 8]);
            }
        }
        bf8 bfr[3];
        #pragma unroll
        for (int g = 0; g < 3; ++g)
            bfr[g] = *(const bf8*)&w_s[buf][(lg * 192 + g * 64 + coln) * 8];
        #pragma unroll
        for (int mf = 0; mf < 4; ++mf) {
            bf8 af = *(const bf8*)&a_s[buf][(lg * 64 + mf * 16 + lr) * 8];
            #pragma unroll
            for (int g = 0; g < 3; ++g)
                acc[mf][g] = __builtin_amdgcn_mfma_f32_16x16x32_bf16(af, bfr[g], acc[mf][g], 0, 0, 0);
        }
        __syncthreads();
        buf ^= 1;
    }

    // ---- phase 3: activations + c/h update (lane-local) ----
    {
        float bi = Wi_b[d * 64 + coln];
        float bff = Wf_b[d * 64 + coln];
        float bo = Wo_b[d * 64 + coln];
        #pragma unroll
        for (int mf = 0; mf < 4; ++mf) {
            #pragma unroll
            for (int r = 0; r < 4; ++r) {
                int row = mf * 16 + lg * 4 + r;
                size_t ci = (size_t)(b0 + row) * DN_ + d * 64 + coln;
                float iv = sigmoidf_fast(acc[mf][0][r] + bi);
                float fv = sigmoidf_fast(acc[mf][1][r] + bff);
                float ov = sigmoidf_fast(acc[mf][2][r] + bo);
                float cn = c_st[ci] * fv + iv * jr[mf][r];
                c_st[ci] = cn;
                float hn = ov * tanhf_fast(cn);
                hn_s[row][coln] = hn;
                inp_nxt[((size_t)(2 + 8 * d + (coln >> 3)) * 1024 + b0 + row) * 8
                        + (coln & 7)] = f2bf(hn);
                if (t == T_ - 1) hT[ci] = hn;
            }
        }
    }
    __syncthreads();

    // ---- phase 4: online alpha accumulation ----
    {
        int b = tid >> 2, q = tid & 3;
        float s = 0.0f;
        #pragma unroll
        for (int i = 0; i < 16; ++i) s += hn_s[b][q * 16 + i] * fa_s[q * 16 + i];
        s += __shfl_xor(s, 1);
        s += __shfl_xor(s, 2);
        float e = __expf(tanhf_fast(s + F_anb[d]));
        float* seh = &Seh[((size_t)(b0 + b) * D_ + d) * 64];
        #pragma unroll
        for (int i = 0; i < 16; ++i) {
            int n = q * 16 + i;
            seh[n] += e * hn_s[b][n];
        }
        if (q == 0) Se[(size_t)(b0 + b) * D_ + d] += e;
    }

    // ---- write x_{t+1} bf16 into next inp buffer (granules 0..1) ----
    if (d == 0 && t + 1 < T_) {
        int b = tid >> 2, q = tid & 3;
        float4 xv = *(const float4*)&x[(size_t)(b0 + b) * (T_ * D_) + (t + 1) * D_ + q * 4];
        ushort4 pk = make_ushort4(f2bf(xv.x), f2bf(xv.y), f2bf(xv.z), f2bf(xv.w));
        *(ushort4*)&inp_nxt[((size_t)(q >> 1) * 1024 + b0 + b) * 8 + (q & 1) * 4] = pk;
    }
}

// ---- epilogue ----
__global__ __launch_bounds__(64)
void final_kernel(const float* __restrict__ hT,
                  const float* __restrict__ Se, const float* __restrict__ Seh,
                  const float* __restrict__ F_bw, const float* __restrict__ F_bb,
                  const float* __restrict__ Phi_w, const float* __restrict__ Phi_b,
                  float* __restrict__ out)
{
    int b = blockIdx.x;
    int tid = threadIdx.x;
    int d = tid >> 2, q = tid & 3;
    float se_inv = 1.0f / Se[(size_t)b * D_ + d];
    float mu = 0.0f, be = 0.0f;
    #pragma unroll
    for (int i = 0; i < 32; ++i) {
        int k = q * 32 + i;
        float hg = (k < 64) ? Seh[((size_t)b * D_ + d) * 64 + k] * se_inv
                            : hT[(size_t)b * DN_ + d * 64 + (k - 64)];
        mu += hg * Phi_w[k];
        be += hg * F_bw[k];
    }
    mu += __shfl_xor(mu, 1); mu += __shfl_xor(mu, 2);
    be += __shfl_xor(be, 1); be += __shfl_xor(be, 2);
    float mud = mu + Phi_b[0];
    float br  = __expf(tanhf_fast(be + F_bb[0]));
    float num = br * mud, den = br;
    #pragma unroll
    for (int off = 4; off < 64; off <<= 1) {
        num += __shfl_xor(num, off);
        den += __shfl_xor(den, off);
    }
    if (tid == 0) out[b] = num / den;
}

extern "C" void kernel_launch(void* const* d_in, const int* in_sizes, int n_in,
                              void* d_out, int out_size, void* d_ws, size_t ws_size,
                              hipStream_t stream)
{
    (void)in_sizes; (void)n_in; (void)out_size; (void)ws_size;
    const float* x     = (const float*)d_in[0];
    const float* U_j   = (const float*)d_in[1];
    const float* W_j   = (const float*)d_in[2];
    const float* b_j   = (const float*)d_in[3];
    const float* Wi_w  = (const float*)d_in[4];
    const float* Wi_b  = (const float*)d_in[5];
    const float* Wf_w  = (const float*)d_in[6];
    const float* Wf_b  = (const float*)d_in[7];
    const float* Wo_w  = (const float*)d_in[8];
    const float* Wo_b  = (const float*)d_in[9];
    const float* F_an  = (const float*)d_in[10];
    const float* F_anb = (const float*)d_in[11];
    const float* F_bw  = (const float*)d_in[12];
    const float* F_bb  = (const float*)d_in[13];
    const float* Phi_w = (const float*)d_in[14];
    const float* Phi_b = (const float*)d_in[15];
    float* out = (float*)d_out;

    char* ws = (char*)d_ws;
    unsigned short* inp[2] = { (unsigned short*)(ws + OFF_INP0),
                               (unsigned short*)(ws + OFF_INP1) };
    float* c_st = (float*)(ws + OFF_C);
    float* Seh  = (float*)(ws + OFF_SEH);
    float* Se   = (float*)(ws + OFF_SE);
    float* hT   = (float*)(ws + OFF_HT);
    unsigned short* W2  = (unsigned short*)(ws + OFF_W2);
    unsigned short* Wj2 = (unsigned short*)(ws + OFF_WJ2);

    hipMemsetAsync(d_ws, 0, ZERO_BYTES, stream);
    prep_w2<<<dim3(12672), dim3(256), 0, stream>>>(Wi_w, Wf_w, Wo_w, W2);
    prep_misc<<<dim3(320), dim3(256), 0, stream>>>(W_j, x, Wj2, inp[0]);

    dim3 grid(16, 16), block(256);   // blockIdx.x = d -> same-d blocks share XCD
    for (int t = 0; t < T_; ++t) {
        step_kernel<<<grid, block, 0, stream>>>(t, x,
            U_j, b_j, Wi_b, Wf_b, Wo_b, F_an, F_anb,
            W2, Wj2, inp[t & 1], inp[(t + 1) & 1],
            c_st, hT, Se, Seh);
    }
    final_kernel<<<dim3(B_), dim3(64), 0, stream>>>(hT, Se, Seh, F_bw, F_bb, Phi_w, Phi_b, out);
}

// Round 6
// 2604.546 us; speedup vs baseline: 6.8481x; 1.3969x over previous
//
#include <hip/hip_runtime.h>
#include <hip/hip_bf16.h>

// FF_attention_module: sLSTM scan (T=128) + attention epilogue.
// Round 6: Round 5's persistent-scan structure, but launched as a PLAIN
// kernel (hipLaunchCooperativeKernel appears to fail in this harness and
// its error was ignored -> scan never ran; bit-identical absmax across two
// different coherence protocols proves it). Co-residency is guaranteed
// structurally: 97KB LDS -> 1 block/CU, 256 blocks on 256 CUs, and the 16
// sync-groups are independent (no grid-wide barrier), so no deadlock.

namespace {
constexpr int B_  = 1024;
constexpr int T_  = 128;
constexpr int D_  = 16;
constexpr int N_  = 64;
constexpr int DN_ = 1024;
constexpr int NCH = 34;     // 34 K-chunks of 32 (K 1040 padded to 1088)
constexpr int NIV = 17;     // 17 intervals of K=64
constexpr int NGR = 136;    // inp granules: 2 x + 128 h + 6 zero-pad

constexpr size_t INPBUF   = (size_t)NGR * 1024 * 8 * 2;        // 2,228,224
constexpr size_t OFF_INP0 = 0;
constexpr size_t OFF_INP1 = INPBUF;
constexpr size_t OFF_FLAGS= 2 * INPBUF;                        // 4,456,448
constexpr size_t OFF_SEH  = OFF_FLAGS + (size_t)16 * 128 * 4;  // 4,464,640
constexpr size_t OFF_SE   = OFF_SEH + (size_t)B_ * DN_ * 4;
constexpr size_t OFF_HT   = OFF_SE  + (size_t)B_ * D_ * 4;
constexpr size_t OFF_W2   = OFF_HT  + (size_t)B_ * DN_ * 4;
constexpr size_t OFF_WJ2  = OFF_W2  + (size_t)16 * NCH * 6144 * 2;
constexpr size_t ZERO_BYTES = OFF_SEH;   // zero inp0+inp1+flags only
}

typedef __attribute__((ext_vector_type(8))) __bf16 bf8;
typedef __attribute__((ext_vector_type(4))) float  f4;
typedef __attribute__((ext_vector_type(4))) unsigned int u32x4;

__device__ __forceinline__ unsigned short f2bf(float v) {
    unsigned int u = __float_as_uint(v);
    unsigned int r = u + 0x7FFFu + ((u >> 16) & 1u);   // RNE
    return (unsigned short)(r >> 16);
}
__device__ __forceinline__ float tanhf_fast(float x) {
    x = fminf(fmaxf(x, -15.0f), 15.0f);
    float e = __expf(2.0f * x);
    return (e - 1.0f) / (e + 1.0f);
}
__device__ __forceinline__ float sigmoidf_fast(float x) {
    return 1.0f / (1.0f + __expf(-x));
}
__device__ __forceinline__ void gl16(const unsigned short* g, unsigned short* l) {
    __builtin_amdgcn_global_load_lds(
        (const __attribute__((address_space(1))) unsigned int*)g,
        (__attribute__((address_space(3))) unsigned int*)l, 16, 0, 0);
}
// coherence-point read (aux 0x11 = sc0|sc1): bypass L1+L2, read LLC
__device__ __forceinline__ void gl16c(const unsigned short* g, unsigned short* l) {
    __builtin_amdgcn_global_load_lds(
        (const __attribute__((address_space(1))) unsigned int*)g,
        (__attribute__((address_space(3))) unsigned int*)l, 16, 0, 17);
}
// coherence-point 16B store: write-through to LLC (sc0 sc1)
__device__ __forceinline__ void st16c(void* gaddr, u32x4 v) {
    unsigned long long a = (unsigned long long)gaddr;
    asm volatile("global_store_dwordx4 %0, %1, off sc0 sc1"
                 :: "v"(a), "v"(v) : "memory");
}
__device__ __forceinline__ void drain_vmem() {
    asm volatile("s_waitcnt vmcnt(0)" ::: "memory");
}

// ---- prep: gate weights fp32 -> bf16 chunk-exact layout ----
// W2 flat: (((d*34 + ch)*4 + kgrp)*192 + col)*8 + e ; col = gate*64 + c
__global__ __launch_bounds__(256)
void prep_w2(const float* __restrict__ Wi, const float* __restrict__ Wf,
             const float* __restrict__ Wo, unsigned short* __restrict__ W2)
{
    int idx = blockIdx.x * 256 + threadIdx.x;
    if (idx >= 16 * NCH * 4 * 192 * 8) return;
    int e    = idx & 7;
    int g3   = idx >> 3;
    int col  = g3 % 192;
    int g2   = g3 / 192;
    int kgrp = g2 & 3;
    int g1   = g2 >> 2;
    int ch   = g1 % NCH;
    int d    = g1 / NCH;
    int k    = ch * 32 + kgrp * 8 + e;
    int gate = col >> 6, c = col & 63;
    float v = 0.0f;
    if (k < 1040) {
        const float* W = (gate == 0) ? Wi : (gate == 1) ? Wf : Wo;
        v = W[(size_t)(d * 64 + c) * 1040 + k];
    }
    W2[idx] = f2bf(v);
}

// Wj2 flat: ((d*8 + kb)*64 + m)*8 + e  (= W_j[d][n=kb*8+e][m]); x(t=0) -> inp0
__global__ __launch_bounds__(256)
void prep_misc(const float* __restrict__ Wj, const float* __restrict__ x,
               unsigned short* __restrict__ Wj2, unsigned short* __restrict__ inp0)
{
    int idx = blockIdx.x * 256 + threadIdx.x;
    if (idx < 65536) {
        int e  = idx & 7;
        int m  = (idx >> 3) & 63;
        int kb = (idx >> 9) & 7;
        int d  = idx >> 12;
        int n  = kb * 8 + e;
        Wj2[idx] = f2bf(Wj[((size_t)d * 64 + n) * 64 + m]);
    } else if (idx < 65536 + 16384) {
        int i2   = idx - 65536;
        int feat = i2 & 15;
        int b    = i2 >> 4;
        float v  = x[(size_t)b * (T_ * D_) + feat];
        inp0[(((size_t)(feat >> 3)) * 1024 + b) * 8 + (feat & 7)] = f2bf(v);
    }
}

// ---- persistent scan kernel: grid (16 d, 16 bt), 256 threads = 4 waves ----
// 97KB LDS -> 1 block/CU -> all 256 blocks co-resident on 256 CUs. The 16
// d-blocks of a bt-group sync through flags; groups are independent.
__global__ __launch_bounds__(256, 1)
void scan_kernel(
    const float* __restrict__ x,
    const float* __restrict__ U_j, const float* __restrict__ b_j,
    const float* __restrict__ Wi_b, const float* __restrict__ Wf_b,
    const float* __restrict__ Wo_b,
    const float* __restrict__ F_an, const float* __restrict__ F_anb,
    const unsigned short* __restrict__ W2, const unsigned short* __restrict__ Wj2,
    unsigned short* __restrict__ inp0, unsigned short* __restrict__ inp1,
    int* __restrict__ flags,
    float* __restrict__ Seh, float* __restrict__ Se, float* __restrict__ hT)
{
    const int d   = blockIdx.x;
    const int bt  = blockIdx.y;
    const int b0  = bt * 64;
    const int tid = threadIdx.x;
    const int wv  = tid >> 6;
    const int ln  = tid & 63;
    const int lr  = ln & 15;
    const int lg  = ln >> 4;
    const int coln = wv * 16 + lr;

    __shared__ __align__(16) unsigned short a_s[2][4096];    // 2 x 8 KB
    __shared__ __align__(16) unsigned short w_s[2][12288];   // 2 x 24 KB
    __shared__ __align__(16) unsigned short jh_s[4096];      // 8 KB
    __shared__ __align__(16) unsigned short wj_s[4096];      // 8 KB
    __shared__ float hn_s[64][65];
    __shared__ float xd_s[64], fa_s[64], e_s[64];

    // hoisted per-lane / per-block constants
    const float uc   = U_j[d * 64 + coln];
    const float bc   = b_j[d * 64 + coln];
    const float bi_c = Wi_b[d * 64 + coln];
    const float bf_c = Wf_b[d * 64 + coln];
    const float bo_c = Wo_b[d * 64 + coln];
    const float fanb = F_anb[d];
    if (tid < 64) fa_s[tid] = F_an[d * 64 + tid];
    #pragma unroll
    for (int i = 0; i < 2; ++i) {    // W_j[d] staged once for all T steps
        int gr = (i * 4 + wv) * 64;
        gl16(Wj2 + (size_t)d * 4096 + (size_t)(gr + ln) * 8, &wj_s[gr * 8]);
    }
    const unsigned short* W2d = W2 + (size_t)d * NCH * 6144;

    float c_r[4][4]   = {};
    float seh_r[4][4] = {};
    float se_r = 0.0f;
    const f4 fz = {0.f, 0.f, 0.f, 0.f};

    for (int t = 0; t < T_; ++t) {
        const unsigned short* cur = (t & 1) ? inp1 : inp0;
        unsigned short*       nxt = (t & 1) ? inp0 : inp1;

        // stage: x_t[:,d], own h d-slice (j input; own writes, LLC-visible),
        // weight interval 0
        if (tid < 64) xd_s[tid] = x[(size_t)(b0 + tid) * (T_ * D_) + t * D_ + d];
        #pragma unroll
        for (int i = 0; i < 2; ++i) {
            int kb = i * 4 + wv;
            gl16c(cur + ((size_t)(2 + 8 * d + kb) * 1024 + b0 + ln) * 8,
                  &jh_s[kb * 512]);
        }
        #pragma unroll
        for (int i = 0; i < 6; ++i) {
            int gr = (i * 4 + wv) * 64;
            gl16(W2d + (size_t)(gr + ln) * 8, &w_s[0][gr * 8]);
        }
        __syncthreads();

        // j = tanh(h_d @ W_j[d] + x_d*u + b_j)
        f4 jacc[4] = {fz, fz, fz, fz};
        #pragma unroll
        for (int ks = 0; ks < 2; ++ks) {
            bf8 bw = *(const bf8*)&wj_s[((ks * 4 + lg) * 64 + coln) * 8];
            #pragma unroll
            for (int mf = 0; mf < 4; ++mf) {
                bf8 ah = *(const bf8*)&jh_s[((ks * 4 + lg) * 64 + mf * 16 + lr) * 8];
                jacc[mf] = __builtin_amdgcn_mfma_f32_16x16x32_bf16(ah, bw, jacc[mf], 0, 0, 0);
            }
        }
        float jr[4][4];
        #pragma unroll
        for (int mf = 0; mf < 4; ++mf)
            #pragma unroll
            for (int r = 0; r < 4; ++r)
                jr[mf][r] = tanhf_fast(jacc[mf][r] + xd_s[mf * 16 + lg * 4 + r] * uc + bc);

        // wait for all 16 d-blocks of this bt-group to have published h_t
        if (t > 0) {
            if (tid == 0) {
                while (__hip_atomic_load(&flags[bt * 128 + t], __ATOMIC_RELAXED,
                                         __HIP_MEMORY_SCOPE_AGENT) < 16)
                    __builtin_amdgcn_s_sleep(1);
            }
            __syncthreads();
        }
        // stage activation interval 0 (LLC-coherent reads)
        #pragma unroll
        for (int i = 0; i < 2; ++i) {
            int gi = i * 4 + wv;
            gl16c(cur + ((size_t)gi * 1024 + b0 + ln) * 8, &a_s[0][gi * 512]);
        }
        __syncthreads();

        // fused 3-gate GEMM over 17 intervals of K=64 (double-buffered)
        f4 acc[4][3];
        #pragma unroll
        for (int mf = 0; mf < 4; ++mf)
            #pragma unroll
            for (int g = 0; g < 3; ++g) acc[mf][g] = fz;

        int buf = 0;
        for (int iv = 0; iv < NIV; ++iv) {
            if (iv < NIV - 1) {
                #pragma unroll
                for (int i = 0; i < 2; ++i) {
                    int gi = i * 4 + wv;
                    gl16c(cur + ((size_t)((iv + 1) * 8 + gi) * 1024 + b0 + ln) * 8,
                          &a_s[buf ^ 1][gi * 512]);
                }
                const unsigned short* wsrc = W2d + (size_t)(iv + 1) * 12288;
                #pragma unroll
                for (int i = 0; i < 6; ++i) {
                    int gr = (i * 4 + wv) * 64;
                    gl16(wsrc + (size_t)(gr + ln) * 8, &w_s[buf ^ 1][gr * 8]);
                }
            }
            #pragma unroll
            for (int ks = 0; ks < 2; ++ks) {
                bf8 bwg[3];
                #pragma unroll
                for (int g = 0; g < 3; ++g)
                    bwg[g] = *(const bf8*)&w_s[buf][ks * 6144 + (lg * 192 + g * 64 + coln) * 8];
                #pragma unroll
                for (int mf = 0; mf < 4; ++mf) {
                    bf8 af = *(const bf8*)&a_s[buf][((ks * 4 + lg) * 64 + mf * 16 + lr) * 8];
                    #pragma unroll
                    for (int g = 0; g < 3; ++g)
                        acc[mf][g] = __builtin_amdgcn_mfma_f32_16x16x32_bf16(af, bwg[g], acc[mf][g], 0, 0, 0);
                }
            }
            __syncthreads();
            buf ^= 1;
        }

        // gates + c/h update (c in registers)
        float hn_r[4][4];
        #pragma unroll
        for (int mf = 0; mf < 4; ++mf) {
            #pragma unroll
            for (int r = 0; r < 4; ++r) {
                int row = mf * 16 + lg * 4 + r;
                float iv_ = sigmoidf_fast(acc[mf][0][r] + bi_c);
                float fv  = sigmoidf_fast(acc[mf][1][r] + bf_c);
                float ov  = sigmoidf_fast(acc[mf][2][r] + bo_c);
                float cn  = c_r[mf][r] * fv + iv_ * jr[mf][r];
                c_r[mf][r] = cn;
                float hn = ov * tanhf_fast(cn);
                hn_r[mf][r] = hn;
                hn_s[row][coln] = hn;
            }
        }
        __syncthreads();

        // publish h_{t+1} (+x_{t+1}) to next inp buffer via LLC stores
        if (t < T_ - 1) {
            #pragma unroll
            for (int i = 0; i < 2; ++i) {
                int g = wv * 2 + i;
                __align__(16) unsigned short pk[8];
                #pragma unroll
                for (int e = 0; e < 8; ++e) pk[e] = f2bf(hn_s[ln][g * 8 + e]);
                st16c(nxt + ((size_t)(2 + 8 * d + g) * 1024 + b0 + ln) * 8,
                      *(const u32x4*)pk);
            }
            if (d == 0 && tid < 64) {
                const float* xr = &x[(size_t)(b0 + tid) * (T_ * D_) + (t + 1) * D_];
                __align__(16) unsigned short pk[16];
                #pragma unroll
                for (int f = 0; f < 16; ++f) pk[f] = f2bf(xr[f]);
                st16c(nxt + ((size_t)(b0 + tid)) * 8,      *(const u32x4*)&pk[0]);
                st16c(nxt + ((size_t)1024 + b0 + tid) * 8, *(const u32x4*)&pk[8]);
            }
            drain_vmem();      // per-wave: asm stores reached the LLC
            __syncthreads();   // all waves drained
            if (tid == 0)
                atomicAdd(&flags[bt * 128 + (t + 1)], 1);   // far-atomic at LLC
        }

        // online alpha accumulation (Seh/Se in registers)
        {
            int b = tid >> 2, q = tid & 3;
            float s = 0.0f;
            #pragma unroll
            for (int i2 = 0; i2 < 16; ++i2) s += hn_s[b][q * 16 + i2] * fa_s[q * 16 + i2];
            s += __shfl_xor(s, 1);
            s += __shfl_xor(s, 2);
            float e = __expf(tanhf_fast(s + fanb));
            if (q == 0) { e_s[b] = e; se_r += e; }
        }
        __syncthreads();
        #pragma unroll
        for (int mf = 0; mf < 4; ++mf)
            #pragma unroll
            for (int r = 0; r < 4; ++r)
                seh_r[mf][r] += e_s[mf * 16 + lg * 4 + r] * hn_r[mf][r];
    }

    // final writes: h_T (from hn_s of t=127), Se, Seh
    {
        int b = tid >> 2, q = tid & 3;
        #pragma unroll
        for (int i2 = 0; i2 < 4; ++i2) {
            float4 v;
            v.x = hn_s[b][q * 16 + i2 * 4 + 0];
            v.y = hn_s[b][q * 16 + i2 * 4 + 1];
            v.z = hn_s[b][q * 16 + i2 * 4 + 2];
            v.w = hn_s[b][q * 16 + i2 * 4 + 3];
            *(float4*)&hT[(size_t)(b0 + b) * DN_ + d * 64 + q * 16 + i2 * 4] = v;
        }
        if (q == 0) Se[(size_t)(b0 + b) * D_ + d] = se_r;
    }
    #pragma unroll
    for (int mf = 0; mf < 4; ++mf)
        #pragma unroll
        for (int r = 0; r < 4; ++r) {
            int row = mf * 16 + lg * 4 + r;
            Seh[((size_t)(b0 + row) * D_ + d) * 64 + coln] = seh_r[mf][r];
        }
}

// ---- epilogue ----
__global__ __launch_bounds__(64)
void final_kernel(const float* __restrict__ hT,
                  const float* __restrict__ Se, const float* __restrict__ Seh,
                  const float* __restrict__ F_bw, const float* __restrict__ F_bb,
                  const float* __restrict__ Phi_w, const float* __restrict__ Phi_b,
                  float* __restrict__ out)
{
    int b = blockIdx.x;
    int tid = threadIdx.x;
    int d = tid >> 2, q = tid & 3;
    float se_inv = 1.0f / Se[(size_t)b * D_ + d];
    float mu = 0.0f, be = 0.0f;
    #pragma unroll
    for (int i = 0; i < 32; ++i) {
        int k = q * 32 + i;
        float hg = (k < 64) ? Seh[((size_t)b * D_ + d) * 64 + k] * se_inv
                            : hT[(size_t)b * DN_ + d * 64 + (k - 64)];
        mu += hg * Phi_w[k];
        be += hg * F_bw[k];
    }
    mu += __shfl_xor(mu, 1); mu += __shfl_xor(mu, 2);
    be += __shfl_xor(be, 1); be += __shfl_xor(be, 2);
    float mud = mu + Phi_b[0];
    float br  = __expf(tanhf_fast(be + F_bb[0]));
    float num = br * mud, den = br;
    #pragma unroll
    for (int off = 4; off < 64; off <<= 1) {
        num += __shfl_xor(num, off);
        den += __shfl_xor(den, off);
    }
    if (tid == 0) out[b] = num / den;
}

extern "C" void kernel_launch(void* const* d_in, const int* in_sizes, int n_in,
                              void* d_out, int out_size, void* d_ws, size_t ws_size,
                              hipStream_t stream)
{
    (void)in_sizes; (void)n_in; (void)out_size; (void)ws_size;
    const float* x     = (const float*)d_in[0];
    const float* U_j   = (const float*)d_in[1];
    const float* W_j   = (const float*)d_in[2];
    const float* b_j   = (const float*)d_in[3];
    const float* Wi_w  = (const float*)d_in[4];
    const float* Wi_b  = (const float*)d_in[5];
    const float* Wf_w  = (const float*)d_in[6];
    const float* Wf_b  = (const float*)d_in[7];
    const float* Wo_w  = (const float*)d_in[8];
    const float* Wo_b  = (const float*)d_in[9];
    const float* F_an  = (const float*)d_in[10];
    const float* F_anb = (const float*)d_in[11];
    const float* F_bw  = (const float*)d_in[12];
    const float* F_bb  = (const float*)d_in[13];
    const float* Phi_w = (const float*)d_in[14];
    const float* Phi_b = (const float*)d_in[15];
    float* out = (float*)d_out;

    char* ws = (char*)d_ws;
    unsigned short* inp0 = (unsigned short*)(ws + OFF_INP0);
    unsigned short* inp1 = (unsigned short*)(ws + OFF_INP1);
    int*   flags = (int*)(ws + OFF_FLAGS);
    float* Seh   = (float*)(ws + OFF_SEH);
    float* Se    = (float*)(ws + OFF_SE);
    float* hT    = (float*)(ws + OFF_HT);
    unsigned short* W2  = (unsigned short*)(ws + OFF_W2);
    unsigned short* Wj2 = (unsigned short*)(ws + OFF_WJ2);

    (void)hipMemsetAsync(d_ws, 0, ZERO_BYTES, stream);
    prep_w2<<<dim3(13056), dim3(256), 0, stream>>>(Wi_w, Wf_w, Wo_w, W2);
    prep_misc<<<dim3(320), dim3(256), 0, stream>>>(W_j, x, Wj2, inp0);

    // plain launch: 1 block/CU (97KB LDS), 256 blocks = 256 CUs -> co-resident
    scan_kernel<<<dim3(16, 16), dim3(256), 0, stream>>>(
        x, U_j, b_j, Wi_b, Wf_b, Wo_b, F_an, F_anb,
        W2, Wj2, inp0, inp1, flags, Seh, Se, hT);

    final_kernel<<<dim3(B_), dim3(64), 0, stream>>>(hT, Se, Seh, F_bw, F_bb,
                                                    Phi_w, Phi_b, out);
}

// Round 7
// 1423.966 us; speedup vs baseline: 12.5258x; 1.8291x over previous
//
#include <hip/hip_runtime.h>
#include <hip/hip_bf16.h>

// FF_attention_module: sLSTM scan (T=128) + attention epilogue.
// Round 7: persistent scan, plain launch (R6 protocol unchanged).
// New: 9 intervals of K=128 (x-first layout), 512 threads (8 waves),
// j-GEMM fused into the interval loop, rcp-based activations, LDS overlay.

namespace {
constexpr int B_  = 1024;
constexpr int T_  = 128;
constexpr int D_  = 16;
constexpr int DN_ = 1024;
constexpr int NIV = 9;       // 9 intervals of K=128 (K_pad = 1152)
constexpr int NGR = 144;     // inp granules: 2 x + 14 pad + 128 h

constexpr size_t INPBUF   = (size_t)NGR * 1024 * 8 * 2;          // 2,359,296
constexpr size_t OFF_INP0 = 0;
constexpr size_t OFF_INP1 = INPBUF;
constexpr size_t OFF_FLAGS= 2 * INPBUF;                          // 4,718,592
constexpr size_t OFF_SEH  = OFF_FLAGS + (size_t)16 * 128 * 4;
constexpr size_t OFF_SE   = OFF_SEH + (size_t)B_ * DN_ * 4;
constexpr size_t OFF_HT   = OFF_SE  + (size_t)B_ * D_ * 4;
constexpr size_t OFF_W2   = OFF_HT  + (size_t)B_ * DN_ * 4;
constexpr size_t OFF_WJ2  = OFF_W2  + (size_t)16 * 9 * 24576 * 2;
constexpr size_t ZERO_BYTES = OFF_SEH;     // zero inp0+inp1+flags only
}

typedef __attribute__((ext_vector_type(8))) __bf16 bf8;
typedef __attribute__((ext_vector_type(4))) float  f4;
typedef __attribute__((ext_vector_type(4))) unsigned int u32x4;

__device__ __forceinline__ unsigned short f2bf(float v) {
    unsigned int u = __float_as_uint(v);
    unsigned int r = u + 0x7FFFu + ((u >> 16) & 1u);   // RNE
    return (unsigned short)(r >> 16);
}
__device__ __forceinline__ float rcpf(float x) { return __builtin_amdgcn_rcpf(x); }
__device__ __forceinline__ float tanhf_fast(float x) {
    x = fminf(fmaxf(x, -15.0f), 15.0f);
    float e = __expf(2.0f * x);
    return (e - 1.0f) * rcpf(e + 1.0f);
}
__device__ __forceinline__ float sigmoidf_fast(float x) {
    return rcpf(1.0f + __expf(-x));
}
__device__ __forceinline__ void gl16(const unsigned short* g, unsigned short* l) {
    __builtin_amdgcn_global_load_lds(
        (const __attribute__((address_space(1))) unsigned int*)g,
        (__attribute__((address_space(3))) unsigned int*)l, 16, 0, 0);
}
// coherence-point read (aux 0x11 = sc0|sc1): bypass L1+L2, read LLC
__device__ __forceinline__ void gl16c(const unsigned short* g, unsigned short* l) {
    __builtin_amdgcn_global_load_lds(
        (const __attribute__((address_space(1))) unsigned int*)g,
        (__attribute__((address_space(3))) unsigned int*)l, 16, 0, 17);
}
// coherence-point 16B store: write-through to LLC (sc0 sc1)
__device__ __forceinline__ void st16c(void* gaddr, u32x4 v) {
    unsigned long long a = (unsigned long long)gaddr;
    asm volatile("global_store_dwordx4 %0, %1, off sc0 sc1"
                 :: "v"(a), "v"(v) : "memory");
}
__device__ __forceinline__ void drain_vmem() {
    asm volatile("s_waitcnt vmcnt(0)" ::: "memory");
}

// ---- prep: gate weights fp32 -> bf16, 9-interval chunk-exact layout ----
// W2 flat (shorts): ((((d*9 + iv)*16 + kg)*192 + col)*8 + e)
// k' = iv*128 + kg*8 + e; k'<16 -> x col k', 16<=k'<128 -> zero pad,
// k'>=128 -> h index k = 16 + (k'-128). col = gate*64 + c.
__global__ __launch_bounds__(256)
void prep_w2(const float* __restrict__ Wi, const float* __restrict__ Wf,
             const float* __restrict__ Wo, unsigned short* __restrict__ W2)
{
    int idx = blockIdx.x * 256 + threadIdx.x;
    if (idx >= 16 * 9 * 16 * 192 * 8) return;
    int e   = idx & 7;
    int t1  = idx >> 3;
    int col = t1 % 192;
    int t2  = t1 / 192;
    int kg  = t2 & 15;
    int t3  = t2 >> 4;
    int iv  = t3 % 9;
    int d   = t3 / 9;
    int kp  = iv * 128 + kg * 8 + e;
    int gate = col >> 6, c = col & 63;
    float v = 0.0f;
    if (kp < 16 || kp >= 128) {
        int k = (kp < 16) ? kp : (16 + (kp - 128));
        const float* W = (gate == 0) ? Wi : (gate == 1) ? Wf : Wo;
        v = W[(size_t)(d * 64 + c) * 1040 + k];
    }
    W2[idx] = f2bf(v);
}

// Wj2 flat: ((d*8 + kb)*64 + m)*8 + e  (= W_j[d][n=kb*8+e][m]); x(t=0) -> inp0
__global__ __launch_bounds__(256)
void prep_misc(const float* __restrict__ Wj, const float* __restrict__ x,
               unsigned short* __restrict__ Wj2, unsigned short* __restrict__ inp0)
{
    int idx = blockIdx.x * 256 + threadIdx.x;
    if (idx < 65536) {
        int e  = idx & 7;
        int m  = (idx >> 3) & 63;
        int kb = (idx >> 9) & 7;
        int d  = idx >> 12;
        int n  = kb * 8 + e;
        Wj2[idx] = f2bf(Wj[((size_t)d * 64 + n) * 64 + m]);
    } else if (idx < 65536 + 16384) {
        int i2   = idx - 65536;
        int feat = i2 & 15;
        int b    = i2 >> 4;
        float v  = x[(size_t)b * (T_ * D_) + feat];
        inp0[(((size_t)(feat >> 3)) * 1024 + b) * 8 + (feat & 7)] = f2bf(v);
    }
}

// ---- persistent scan: grid (16 d, 16 bt), 512 threads = 8 waves ----
// wave = (cw 0..3 col-group, rw 0..1 row-group); 1 block/CU (137KB LDS).
__global__ __launch_bounds__(512, 1)
void scan_kernel(
    const float* __restrict__ x,
    const float* __restrict__ U_j, const float* __restrict__ b_j,
    const float* __restrict__ Wi_b, const float* __restrict__ Wf_b,
    const float* __restrict__ Wo_b,
    const float* __restrict__ F_an, const float* __restrict__ F_anb,
    const unsigned short* __restrict__ W2, const unsigned short* __restrict__ Wj2,
    unsigned short* __restrict__ inp0, unsigned short* __restrict__ inp1,
    int* __restrict__ flags,
    float* __restrict__ Seh, float* __restrict__ Se, float* __restrict__ hT)
{
    const int d   = blockIdx.x;
    const int bt  = blockIdx.y;
    const int b0  = bt * 64;
    const int tid = threadIdx.x;
    const int wv  = tid >> 6;        // 0..7
    const int cw  = wv & 3;
    const int rw  = wv >> 2;
    const int ln  = tid & 63;
    const int lr  = ln & 15;
    const int lg  = ln >> 4;
    const int coln  = cw * 16 + lr;          // gate column within d-slice
    const int rbase = rw * 32;               // + mf*16 + ... batch-row base

    // LDS: [a0 16K][a1 16K][w 2x48K][wj 8K][xd/fa/e 768B]; hn overlays a.
    __shared__ __align__(16) unsigned char smem[140032];
    unsigned short* a_sb0 = (unsigned short*)smem;
    unsigned short* a_sb1 = (unsigned short*)(smem + 16384);
    unsigned short* w_sb  = (unsigned short*)(smem + 32768);   // 2 x 24576 shorts
    unsigned short* wj_s  = (unsigned short*)(smem + 131072);  // 4096 shorts
    float* xd_s = (float*)(smem + 139264);
    float* fa_s = xd_s + 64;
    float* e_s  = xd_s + 128;
    typedef float (*hnrow_t)[66];
    hnrow_t hn_s = (hnrow_t)smem;            // 64x66 f32 = 16.9KB overlay

    const float uc   = U_j[d * 64 + coln];
    const float bc   = b_j[d * 64 + coln];
    const float bi_c = Wi_b[d * 64 + coln];
    const float bf_c = Wf_b[d * 64 + coln];
    const float bo_c = Wo_b[d * 64 + coln];
    const float fanb = F_anb[d];
    if (tid < 64) fa_s[tid] = F_an[d * 64 + tid];
    gl16(Wj2 + (size_t)d * 4096 + (size_t)wv * 512 + (size_t)ln * 8,
         wj_s + wv * 512);
    const unsigned short* W2d = W2 + (size_t)d * (9 * 24576);
    const int jiv = 1 + (d >> 1);        // interval holding own h d-slice
    const int jgb = (d & 1) * 8;         // granule base of slice in interval

    float c_r[2][4]   = {};
    float seh_r[2][4] = {};
    float se_r = 0.0f;
    const f4 fz = {0.f, 0.f, 0.f, 0.f};

    for (int t = 0; t < T_; ++t) {
        const unsigned short* cur = (t & 1) ? inp1 : inp0;
        unsigned short*       nxt = (t & 1) ? inp0 : inp1;

        // ---- pre-flag work: x_t[:,d] + weight interval 0 (no h dependency)
        if (tid < 64) xd_s[tid] = x[(size_t)(b0 + tid) * (T_ * D_) + t * D_ + d];
        #pragma unroll
        for (int i = 0; i < 6; ++i) {
            int g = wv * 6 + i;
            gl16(W2d + (size_t)g * 512 + (size_t)ln * 8, w_sb + g * 512);
        }
        if (t > 0) {
            if (tid == 0) {
                while (__hip_atomic_load(&flags[bt * 128 + t], __ATOMIC_RELAXED,
                                         __HIP_MEMORY_SCOPE_AGENT) < 16)
                    __builtin_amdgcn_s_sleep(1);
            }
        }
        __syncthreads();                 // w0 drained + flag visible
        #pragma unroll
        for (int i = 0; i < 2; ++i) {    // a interval 0 (coherent)
            int g = wv * 2 + i;
            gl16c(cur + ((size_t)g * 1024 + b0 + ln) * 8, a_sb0 + g * 512);
        }
        __syncthreads();                 // a0 drained

        // ---- 9 intervals of K=128, double-buffered; j fused at iv==jiv ----
        f4 acc[2][3] = {{fz, fz, fz}, {fz, fz, fz}};
        f4 jacc[2]   = {fz, fz};
        int buf = 0;
        for (int iv = 0; iv < NIV; ++iv) {
            unsigned short* a_cur = buf ? a_sb1 : a_sb0;
            if (iv < NIV - 1) {
                unsigned short* a_nxt = buf ? a_sb0 : a_sb1;
                #pragma unroll
                for (int i = 0; i < 2; ++i) {
                    int g = wv * 2 + i;
                    gl16c(cur + ((size_t)((iv + 1) * 16 + g) * 1024 + b0 + ln) * 8,
                          a_nxt + g * 512);
                }
                const unsigned short* wsrc = W2d + (size_t)(iv + 1) * 24576;
                unsigned short* w_nxt = w_sb + (buf ^ 1) * 24576;
                #pragma unroll
                for (int i = 0; i < 6; ++i) {
                    int g = wv * 6 + i;
                    gl16(wsrc + (size_t)g * 512 + (size_t)ln * 8, w_nxt + g * 512);
                }
            }
            const unsigned short* w_cur = w_sb + buf * 24576;
            #pragma unroll
            for (int ks = 0; ks < 4; ++ks) {
                int kg = ks * 4 + lg;
                bf8 bwg[3];
                #pragma unroll
                for (int g = 0; g < 3; ++g)
                    bwg[g] = *(const bf8*)&w_cur[(kg * 192 + g * 64 + coln) * 8];
                #pragma unroll
                for (int mf = 0; mf < 2; ++mf) {
                    bf8 af = *(const bf8*)&a_cur[kg * 512 + (rbase + mf * 16 + lr) * 8];
                    #pragma unroll
                    for (int g = 0; g < 3; ++g)
                        acc[mf][g] = __builtin_amdgcn_mfma_f32_16x16x32_bf16(
                            af, bwg[g], acc[mf][g], 0, 0, 0);
                }
            }
            if (iv == jiv) {             // j = h_d @ W_j[d] (block-uniform)
                #pragma unroll
                for (int ks2 = 0; ks2 < 2; ++ks2) {
                    bf8 bw = *(const bf8*)&wj_s[((ks2 * 4 + lg) * 64 + coln) * 8];
                    #pragma unroll
                    for (int mf = 0; mf < 2; ++mf) {
                        bf8 ah = *(const bf8*)&a_cur[(jgb + ks2 * 4 + lg) * 512
                                                     + (rbase + mf * 16 + lr) * 8];
                        jacc[mf] = __builtin_amdgcn_mfma_f32_16x16x32_bf16(
                            ah, bw, jacc[mf], 0, 0, 0);
                    }
                }
            }
            __syncthreads();
            buf ^= 1;
        }

        // ---- gates + c/h update (all lane-local) ----
        float hn_r[2][4];
        #pragma unroll
        for (int mf = 0; mf < 2; ++mf) {
            #pragma unroll
            for (int r = 0; r < 4; ++r) {
                int row = rbase + mf * 16 + lg * 4 + r;
                float jr  = tanhf_fast(jacc[mf][r] + xd_s[row] * uc + bc);
                float iv_ = sigmoidf_fast(acc[mf][0][r] + bi_c);
                float fv  = sigmoidf_fast(acc[mf][1][r] + bf_c);
                float ov  = sigmoidf_fast(acc[mf][2][r] + bo_c);
                float cn  = c_r[mf][r] * fv + iv_ * jr;
                c_r[mf][r] = cn;
                float hn = ov * tanhf_fast(cn);
                hn_r[mf][r] = hn;
                hn_s[row][coln] = hn;
            }
        }
        __syncthreads();

        // ---- publish h_{t+1} (+x_{t+1}) via LLC stores; post flag ----
        if (t < T_ - 1) {
            {   // wave wv stores granule wv of this d-slice (row = ln)
                __align__(16) unsigned short pk[8];
                #pragma unroll
                for (int e = 0; e < 8; ++e) pk[e] = f2bf(hn_s[ln][wv * 8 + e]);
                st16c(nxt + ((size_t)(16 + 8 * d + wv) * 1024 + b0 + ln) * 8,
                      *(const u32x4*)pk);
            }
            if (d == 0 && tid < 64) {
                const float* xr = &x[(size_t)(b0 + tid) * (T_ * D_) + (t + 1) * D_];
                __align__(16) unsigned short pk[16];
                #pragma unroll
                for (int f = 0; f < 16; ++f) pk[f] = f2bf(xr[f]);
                st16c(nxt + ((size_t)(b0 + tid)) * 8,        *(const u32x4*)&pk[0]);
                st16c(nxt + ((size_t)1024 + b0 + tid) * 8,   *(const u32x4*)&pk[8]);
            }
            drain_vmem();
            __syncthreads();
            if (tid == 0)
                atomicAdd(&flags[bt * 128 + (t + 1)], 1);
        }

        // ---- online alpha accumulation ----
        {
            int br_ = tid >> 3, q = tid & 7;
            float s = 0.0f;
            #pragma unroll
            for (int i2 = 0; i2 < 8; ++i2)
                s += hn_s[br_][q * 8 + i2] * fa_s[q * 8 + i2];
            s += __shfl_xor(s, 1);
            s += __shfl_xor(s, 2);
            s += __shfl_xor(s, 4);
            float e = __expf(tanhf_fast(s + fanb));
            if (q == 0) { e_s[br_] = e; se_r += e; }
        }
        __syncthreads();
        #pragma unroll
        for (int mf = 0; mf < 2; ++mf)
            #pragma unroll
            for (int r = 0; r < 4; ++r)
                seh_r[mf][r] += e_s[rbase + mf * 16 + lg * 4 + r] * hn_r[mf][r];
    }

    // ---- final writes: hT (t=127 h from hn_s), Se, Seh ----
    {
        int br_ = tid >> 3, q = tid & 7;
        #pragma unroll
        for (int i2 = 0; i2 < 2; ++i2) {
            float4 v;
            v.x = hn_s[br_][q * 8 + i2 * 4 + 0];
            v.y = hn_s[br_][q * 8 + i2 * 4 + 1];
            v.z = hn_s[br_][q * 8 + i2 * 4 + 2];
            v.w = hn_s[br_][q * 8 + i2 * 4 + 3];
            *(float4*)&hT[(size_t)(b0 + br_) * DN_ + d * 64 + q * 8 + i2 * 4] = v;
        }
        if (q == 0) Se[(size_t)(b0 + br_) * D_ + d] = se_r;
    }
    #pragma unroll
    for (int mf = 0; mf < 2; ++mf)
        #pragma unroll
        for (int r = 0; r < 4; ++r) {
            int row = rbase + mf * 16 + lg * 4 + r;
            Seh[((size_t)(b0 + row) * D_ + d) * 64 + coln] = seh_r[mf][r];
        }
}

// ---- epilogue ----
__global__ __launch_bounds__(64)
void final_kernel(const float* __restrict__ hT,
                  const float* __restrict__ Se, const float* __restrict__ Seh,
                  const float* __restrict__ F_bw, const float* __restrict__ F_bb,
                  const float* __restrict__ Phi_w, const float* __restrict__ Phi_b,
                  float* __restrict__ out)
{
    int b = blockIdx.x;
    int tid = threadIdx.x;
    int d = tid >> 2, q = tid & 3;
    float se_inv = 1.0f / Se[(size_t)b * D_ + d];
    float mu = 0.0f, be = 0.0f;
    #pragma unroll
    for (int i = 0; i < 32; ++i) {
        int k = q * 32 + i;
        float hg = (k < 64) ? Seh[((size_t)b * D_ + d) * 64 + k] * se_inv
                            : hT[(size_t)b * DN_ + d * 64 + (k - 64)];
        mu += hg * Phi_w[k];
        be += hg * F_bw[k];
    }
    mu += __shfl_xor(mu, 1); mu += __shfl_xor(mu, 2);
    be += __shfl_xor(be, 1); be += __shfl_xor(be, 2);
    float mud = mu + Phi_b[0];
    float br  = __expf(tanhf_fast(be + F_bb[0]));
    float num = br * mud, den = br;
    #pragma unroll
    for (int off = 4; off < 64; off <<= 1) {
        num += __shfl_xor(num, off);
        den += __shfl_xor(den, off);
    }
    if (tid == 0) out[b] = num / den;
}

extern "C" void kernel_launch(void* const* d_in, const int* in_sizes, int n_in,
                              void* d_out, int out_size, void* d_ws, size_t ws_size,
                              hipStream_t stream)
{
    (void)in_sizes; (void)n_in; (void)out_size; (void)ws_size;
    const float* x     = (const float*)d_in[0];
    const float* U_j   = (const float*)d_in[1];
    const float* W_j   = (const float*)d_in[2];
    const float* b_j   = (const float*)d_in[3];
    const float* Wi_w  = (const float*)d_in[4];
    const float* Wi_b  = (const float*)d_in[5];
    const float* Wf_w  = (const float*)d_in[6];
    const float* Wf_b  = (const float*)d_in[7];
    const float* Wo_w  = (const float*)d_in[8];
    const float* Wo_b  = (const float*)d_in[9];
    const float* F_an  = (const float*)d_in[10];
    const float* F_anb = (const float*)d_in[11];
    const float* F_bw  = (const float*)d_in[12];
    const float* F_bb  = (const float*)d_in[13];
    const float* Phi_w = (const float*)d_in[14];
    const float* Phi_b = (const float*)d_in[15];
    float* out = (float*)d_out;

    char* ws = (char*)d_ws;
    unsigned short* inp0 = (unsigned short*)(ws + OFF_INP0);
    unsigned short* inp1 = (unsigned short*)(ws + OFF_INP1);
    int*   flags = (int*)(ws + OFF_FLAGS);
    float* Seh   = (float*)(ws + OFF_SEH);
    float* Se    = (float*)(ws + OFF_SE);
    float* hT    = (float*)(ws + OFF_HT);
    unsigned short* W2  = (unsigned short*)(ws + OFF_W2);
    unsigned short* Wj2 = (unsigned short*)(ws + OFF_WJ2);

    (void)hipMemsetAsync(d_ws, 0, ZERO_BYTES, stream);
    prep_w2<<<dim3(13824), dim3(256), 0, stream>>>(Wi_w, Wf_w, Wo_w, W2);
    prep_misc<<<dim3(320), dim3(256), 0, stream>>>(W_j, x, Wj2, inp0);

    // plain launch: 1 block/CU (137KB LDS), 256 blocks = 256 CUs
    scan_kernel<<<dim3(16, 16), dim3(512), 0, stream>>>(
        x, U_j, b_j, Wi_b, Wf_b, Wo_b, F_an, F_anb,
        W2, Wj2, inp0, inp1, flags, Seh, Se, hT);

    final_kernel<<<dim3(B_), dim3(64), 0, stream>>>(hT, Se, Seh, F_bw, F_bb,
                                                    Phi_w, Phi_b, out);
}

// Round 9
// 1370.429 us; speedup vs baseline: 13.0151x; 1.0391x over previous
//
#include <hip/hip_runtime.h>
#include <hip/hip_bf16.h>

// FF_attention_module: sLSTM scan (T=128) + attention epilogue.
// Round 9: R8 with the wx_s staging bug fixed (12 granules, was 6 ->
// uninitialized LDS -> NaN). XCD-aware 1D grid, 8 uniform K=128
// h-intervals, x-part via resident Wx MFMA accumulator init.

namespace {
constexpr int B_  = 1024;
constexpr int T_  = 128;
constexpr int D_  = 16;
constexpr int DN_ = 1024;
constexpr int NIV = 8;       // 8 intervals of K=128 (pure h, 1024 total)

constexpr size_t INPBUF   = (size_t)128 * 1024 * 8 * 2;      // 2,097,152
constexpr size_t OFF_INP0 = 0;
constexpr size_t OFF_INP1 = INPBUF;
constexpr size_t OFF_FLAGS= 2 * INPBUF;                      // 4,194,304
constexpr size_t OFF_SEH  = OFF_FLAGS + (size_t)16 * 128 * 4;
constexpr size_t OFF_SE   = OFF_SEH + (size_t)B_ * DN_ * 4;
constexpr size_t OFF_HT   = OFF_SE  + (size_t)B_ * D_ * 4;
constexpr size_t OFF_W2   = OFF_HT  + (size_t)B_ * DN_ * 4;
constexpr size_t OFF_WJ2  = OFF_W2  + (size_t)16 * 8 * 24576 * 2;
constexpr size_t OFF_WX2  = OFF_WJ2 + (size_t)16 * 4096 * 2;
constexpr size_t ZERO_BYTES = OFF_SEH;   // zero inp0+inp1+flags only
}

typedef __attribute__((ext_vector_type(8))) __bf16 bf8;
typedef __attribute__((ext_vector_type(4))) float  f4;
typedef __attribute__((ext_vector_type(4))) unsigned int u32x4;

__device__ __forceinline__ unsigned short f2bf(float v) {
    unsigned int u = __float_as_uint(v);
    unsigned int r = u + 0x7FFFu + ((u >> 16) & 1u);   // RNE
    return (unsigned short)(r >> 16);
}
__device__ __forceinline__ float rcpf(float x) { return __builtin_amdgcn_rcpf(x); }
__device__ __forceinline__ float tanhf_fast(float x) {
    x = fminf(fmaxf(x, -15.0f), 15.0f);
    float e = __expf(2.0f * x);
    return (e - 1.0f) * rcpf(e + 1.0f);
}
__device__ __forceinline__ float sigmoidf_fast(float x) {
    return rcpf(1.0f + __expf(-x));
}
__device__ __forceinline__ void gl16(const unsigned short* g, unsigned short* l) {
    __builtin_amdgcn_global_load_lds(
        (const __attribute__((address_space(1))) unsigned int*)g,
        (__attribute__((address_space(3))) unsigned int*)l, 16, 0, 0);
}
// coherence-point read (aux 0x11 = sc0|sc1)
__device__ __forceinline__ void gl16c(const unsigned short* g, unsigned short* l) {
    __builtin_amdgcn_global_load_lds(
        (const __attribute__((address_space(1))) unsigned int*)g,
        (__attribute__((address_space(3))) unsigned int*)l, 16, 0, 17);
}
// coherence-point 16B store (sc0 sc1)
__device__ __forceinline__ void st16c(void* gaddr, u32x4 v) {
    unsigned long long a = (unsigned long long)gaddr;
    asm volatile("global_store_dwordx4 %0, %1, off sc0 sc1"
                 :: "v"(a), "v"(v) : "memory");
}
__device__ __forceinline__ void drain_vmem() {
    asm volatile("s_waitcnt vmcnt(0)" ::: "memory");
}

// ---- prep: gate weights fp32 -> bf16, 8 uniform K=128 h-intervals ----
// W2 flat (shorts): (((d*8 + iv)*16 + kg)*192 + col)*8 + e
// original k = 16 + iv*128 + kg*8 + e ; col = gate*64 + c
__global__ __launch_bounds__(256)
void prep_w2(const float* __restrict__ Wi, const float* __restrict__ Wf,
             const float* __restrict__ Wo, unsigned short* __restrict__ W2)
{
    int idx = blockIdx.x * 256 + threadIdx.x;
    if (idx >= 16 * 8 * 16 * 192 * 8) return;
    int e   = idx & 7;
    int t1  = idx >> 3;
    int col = t1 % 192;
    int t2  = t1 / 192;
    int kg  = t2 & 15;
    int t3  = t2 >> 4;
    int iv  = t3 & 7;
    int d   = t3 >> 3;
    int k   = 16 + iv * 128 + kg * 8 + e;
    int gate = col >> 6, c = col & 63;
    const float* W = (gate == 0) ? Wi : (gate == 1) ? Wf : Wo;
    W2[idx] = f2bf(W[(size_t)(d * 64 + c) * 1040 + k]);
}

// Wj2: ((d*8 + kb)*64 + m)*8 + e  (= W_j[d][n=kb*8+e][m])
// Wx2: ((d*4 + kg)*192 + col)*8 + e  (= Wgate[d*64+c][k=kg*8+e], 0 for k>=16)
__global__ __launch_bounds__(256)
void prep_misc(const float* __restrict__ Wj,
               const float* __restrict__ Wi, const float* __restrict__ Wf,
               const float* __restrict__ Wo,
               unsigned short* __restrict__ Wj2, unsigned short* __restrict__ Wx2)
{
    int idx = blockIdx.x * 256 + threadIdx.x;
    if (idx < 65536) {
        int e  = idx & 7;
        int m  = (idx >> 3) & 63;
        int kb = (idx >> 9) & 7;
        int d  = idx >> 12;
        int n  = kb * 8 + e;
        Wj2[idx] = f2bf(Wj[((size_t)d * 64 + n) * 64 + m]);
    } else if (idx < 65536 + 98304) {
        int i2  = idx - 65536;
        int e   = i2 & 7;
        int t1  = i2 >> 3;
        int col = t1 % 192;
        int t2  = t1 / 192;
        int kg  = t2 & 3;
        int d   = t2 >> 2;
        int k   = kg * 8 + e;
        int gate = col >> 6, c = col & 63;
        float v = 0.0f;
        if (k < 16) {
            const float* W = (gate == 0) ? Wi : (gate == 1) ? Wf : Wo;
            v = W[(size_t)(d * 64 + c) * 1040 + k];
        }
        Wx2[i2] = f2bf(v);
    }
}

// ---- persistent scan: 1D grid 256, 512 threads = 8 waves ----
// XCD-aware decode: xcd = id%8 hosts d in {2*xcd, 2*xcd+1} for all bt
// -> per-XCD weight working set = 768 KB (L2-resident).
__global__ __launch_bounds__(512, 1)
void scan_kernel(
    const float* __restrict__ x,
    const float* __restrict__ U_j, const float* __restrict__ b_j,
    const float* __restrict__ Wi_b, const float* __restrict__ Wf_b,
    const float* __restrict__ Wo_b,
    const float* __restrict__ F_an, const float* __restrict__ F_anb,
    const unsigned short* __restrict__ W2, const unsigned short* __restrict__ Wj2,
    const unsigned short* __restrict__ Wx2,
    unsigned short* __restrict__ inp0, unsigned short* __restrict__ inp1,
    int* __restrict__ flags,
    float* __restrict__ Seh, float* __restrict__ Se, float* __restrict__ hT)
{
    const int id  = blockIdx.x;
    const int d   = (id & 7) * 2 + ((id >> 3) & 1);
    const int bt  = id >> 4;
    const int b0  = bt * 64;
    const int tid = threadIdx.x;
    const int wv  = tid >> 6;        // 0..7
    const int cw  = wv & 3;
    const int rw  = wv >> 2;
    const int ln  = tid & 63;
    const int lr  = ln & 15;
    const int lg  = ln >> 4;
    const int coln  = cw * 16 + lr;
    const int rbase = rw * 32;

    // LDS: a 2x16K | w 2x48K | wj 8K | wx 12K | xa 4K | xd/fa/e 768B = 152.8K
    __shared__ __align__(16) unsigned char smem[156416];
    unsigned short* a_sb0 = (unsigned short*)smem;
    unsigned short* a_sb1 = (unsigned short*)(smem + 16384);
    unsigned short* w_sb  = (unsigned short*)(smem + 32768);   // 2 x 24576
    unsigned short* wj_s  = (unsigned short*)(smem + 131072);  // 4096
    unsigned short* wx_s  = (unsigned short*)(smem + 139264);  // 6144
    unsigned short* xa_s  = (unsigned short*)(smem + 151552);  // [64][32]
    float* xd_s = (float*)(smem + 155648);
    float* fa_s = xd_s + 64;
    float* e_s  = xd_s + 128;
    typedef float (*hnrow_t)[66];
    hnrow_t hn_s = (hnrow_t)smem;    // 64x66 f32 overlay on a_s

    const float uc   = U_j[d * 64 + coln];
    const float bc   = b_j[d * 64 + coln];
    const float bi_c = Wi_b[d * 64 + coln];
    const float bf_c = Wf_b[d * 64 + coln];
    const float bo_c = Wo_b[d * 64 + coln];
    const float fanb = F_anb[d];
    if (tid < 64) fa_s[tid] = F_an[d * 64 + tid];
    // one-time stages: Wj (8 granules), Wx (12 granules), xa zero-pad
    gl16(Wj2 + (size_t)d * 4096 + (size_t)(wv * 64 + ln) * 8, wj_s + wv * 512);
    #pragma unroll
    for (int i = 0; i < 2; ++i) {
        int g = wv + i * 8;
        if (g < 12)
            gl16(Wx2 + (size_t)d * 6144 + (size_t)(g * 64 + ln) * 8, wx_s + g * 512);
    }
    *(ushort4*)&xa_s[tid * 4] = make_ushort4(0, 0, 0, 0);
    const unsigned short* W2d = W2 + (size_t)d * (8 * 24576);
    const int jiv = d >> 1;          // interval holding own h d-slice
    const int jgb = (d & 1) * 8;     // granule base within that interval

    float c_r[2][4]   = {};
    float seh_r[2][4] = {};
    float se_r = 0.0f;
    const f4 fz = {0.f, 0.f, 0.f, 0.f};

    for (int t = 0; t < T_; ++t) {
        const unsigned short* cur = (t & 1) ? inp1 : inp0;
        unsigned short*       nxt = (t & 1) ? inp0 : inp1;

        // ---- pre-loop: x staging + weight interval 0 (flag-independent) ----
        if (tid < 64) xd_s[tid] = x[(size_t)(b0 + tid) * 2048 + t * 16 + d];
        if (tid < 256) {
            int b = tid >> 2, q = tid & 3;
            float4 xv = *(const float4*)&x[(size_t)(b0 + b) * 2048 + t * 16 + q * 4];
            *(ushort4*)&xa_s[b * 32 + q * 4] =
                make_ushort4(f2bf(xv.x), f2bf(xv.y), f2bf(xv.z), f2bf(xv.w));
        }
        #pragma unroll
        for (int i = 0; i < 6; ++i) {
            int gw = wv * 6 + i;
            gl16(W2d + (size_t)(gw * 64 + ln) * 8, w_sb + gw * 512);
        }
        if (t > 0) {
            if (tid == 0) {
                while (__hip_atomic_load(&flags[bt * 128 + t], __ATOMIC_RELAXED,
                                         __HIP_MEMORY_SCOPE_AGENT) < 16)
                    __builtin_amdgcn_s_sleep(1);
            }
        }
        __syncthreads();   // flag visible; xa/w0 staged

        // issue act interval 0 (coherent)
        #pragma unroll
        for (int i = 0; i < 2; ++i) {
            int ga = wv * 2 + i;
            gl16c(cur + ((size_t)ga * 1024 + b0 + ln) * 8, a_sb0 + ga * 512);
        }
        // x-chunk MFMA: initialize accumulators (hides part of a0 latency)
        f4 acc[2][3];
        {
            bf8 wxg[3];
            #pragma unroll
            for (int g = 0; g < 3; ++g)
                wxg[g] = *(const bf8*)&wx_s[(lg * 192 + g * 64 + coln) * 8];
            #pragma unroll
            for (int mf = 0; mf < 2; ++mf) {
                bf8 xa = *(const bf8*)&xa_s[(rbase + mf * 16 + lr) * 32 + lg * 8];
                #pragma unroll
                for (int g = 0; g < 3; ++g)
                    acc[mf][g] = __builtin_amdgcn_mfma_f32_16x16x32_bf16(
                        xa, wxg[g], fz, 0, 0, 0);
            }
        }
        f4 jacc[2] = {fz, fz};
        __syncthreads();   // a0 drained

        // ---- 8 intervals of K=128, double-buffered ----
        int buf = 0;
        for (int iv = 0; iv < NIV; ++iv) {
            unsigned short* a_cur = buf ? a_sb1 : a_sb0;
            if (iv < NIV - 1) {
                unsigned short* a_nxt = buf ? a_sb0 : a_sb1;
                #pragma unroll
                for (int i = 0; i < 2; ++i) {   // acts first (longer latency)
                    int ga = wv * 2 + i;
                    gl16c(cur + ((size_t)((iv + 1) * 16 + ga) * 1024 + b0 + ln) * 8,
                          a_nxt + ga * 512);
                }
                const unsigned short* wsrc = W2d + (size_t)(iv + 1) * 24576;
                unsigned short* w_nxt = w_sb + (buf ^ 1) * 24576;
                #pragma unroll
                for (int i = 0; i < 6; ++i) {
                    int gw = wv * 6 + i;
                    gl16(wsrc + (size_t)(gw * 64 + ln) * 8, w_nxt + gw * 512);
                }
            }
            const unsigned short* w_cur = w_sb + buf * 24576;
            #pragma unroll
            for (int ks = 0; ks < 4; ++ks) {
                int kg = ks * 4 + lg;
                bf8 bwg[3];
                #pragma unroll
                for (int g = 0; g < 3; ++g)
                    bwg[g] = *(const bf8*)&w_cur[(kg * 192 + g * 64 + coln) * 8];
                #pragma unroll
                for (int mf = 0; mf < 2; ++mf) {
                    bf8 af = *(const bf8*)&a_cur[kg * 512 + (rbase + mf * 16 + lr) * 8];
                    #pragma unroll
                    for (int g = 0; g < 3; ++g)
                        acc[mf][g] = __builtin_amdgcn_mfma_f32_16x16x32_bf16(
                            af, bwg[g], acc[mf][g], 0, 0, 0);
                }
            }
            if (iv == jiv) {   // j = h_d @ W_j[d]
                #pragma unroll
                for (int ks2 = 0; ks2 < 2; ++ks2) {
                    bf8 bw = *(const bf8*)&wj_s[((ks2 * 4 + lg) * 64 + coln) * 8];
                    #pragma unroll
                    for (int mf = 0; mf < 2; ++mf) {
                        bf8 ah = *(const bf8*)&a_cur[(jgb + ks2 * 4 + lg) * 512
                                                     + (rbase + mf * 16 + lr) * 8];
                        jacc[mf] = __builtin_amdgcn_mfma_f32_16x16x32_bf16(
                            ah, bw, jacc[mf], 0, 0, 0);
                    }
                }
            }
            __syncthreads();
            buf ^= 1;
        }

        // ---- gates + c/h update ----
        float hn_r[2][4];
        #pragma unroll
        for (int mf = 0; mf < 2; ++mf) {
            #pragma unroll
            for (int r = 0; r < 4; ++r) {
                int row = rbase + mf * 16 + lg * 4 + r;
                float jr  = tanhf_fast(jacc[mf][r] + xd_s[row] * uc + bc);
                float iv_ = sigmoidf_fast(acc[mf][0][r] + bi_c);
                float fv  = sigmoidf_fast(acc[mf][1][r] + bf_c);
                float ov  = sigmoidf_fast(acc[mf][2][r] + bo_c);
                float cn  = c_r[mf][r] * fv + iv_ * jr;
                c_r[mf][r] = cn;
                float hn = ov * tanhf_fast(cn);
                hn_r[mf][r] = hn;
                hn_s[row][coln] = hn;
            }
        }
        __syncthreads();

        // ---- publish h_{t+1} via LLC stores; post flag ----
        if (t < T_ - 1) {
            __align__(16) unsigned short pk[8];
            #pragma unroll
            for (int e = 0; e < 8; ++e) pk[e] = f2bf(hn_s[ln][wv * 8 + e]);
            st16c(nxt + ((size_t)(d * 8 + wv) * 1024 + b0 + ln) * 8,
                  *(const u32x4*)pk);
            drain_vmem();
            __syncthreads();
            if (tid == 0)
                atomicAdd(&flags[bt * 128 + (t + 1)], 1);
        }

        // ---- online alpha accumulation ----
        {
            int br_ = tid >> 3, q = tid & 7;
            float s = 0.0f;
            #pragma unroll
            for (int i2 = 0; i2 < 8; ++i2)
                s += hn_s[br_][q * 8 + i2] * fa_s[q * 8 + i2];
            s += __shfl_xor(s, 1);
            s += __shfl_xor(s, 2);
            s += __shfl_xor(s, 4);
            float e = __expf(tanhf_fast(s + fanb));
            if (q == 0) { e_s[br_] = e; se_r += e; }
        }
        __syncthreads();
        #pragma unroll
        for (int mf = 0; mf < 2; ++mf)
            #pragma unroll
            for (int r = 0; r < 4; ++r)
                seh_r[mf][r] += e_s[rbase + mf * 16 + lg * 4 + r] * hn_r[mf][r];
    }

    // ---- final writes: hT (t=127 h), Se, Seh ----
    {
        int br_ = tid >> 3, q = tid & 7;
        #pragma unroll
        for (int i2 = 0; i2 < 2; ++i2) {
            float4 v;
            v.x = hn_s[br_][q * 8 + i2 * 4 + 0];
            v.y = hn_s[br_][q * 8 + i2 * 4 + 1];
            v.z = hn_s[br_][q * 8 + i2 * 4 + 2];
            v.w = hn_s[br_][q * 8 + i2 * 4 + 3];
            *(float4*)&hT[(size_t)(b0 + br_) * DN_ + d * 64 + q * 8 + i2 * 4] = v;
        }
        if (q == 0) Se[(size_t)(b0 + br_) * D_ + d] = se_r;
    }
    #pragma unroll
    for (int mf = 0; mf < 2; ++mf)
        #pragma unroll
        for (int r = 0; r < 4; ++r) {
            int row = rbase + mf * 16 + lg * 4 + r;
            Seh[((size_t)(b0 + row) * D_ + d) * 64 + coln] = seh_r[mf][r];
        }
}

// ---- epilogue ----
__global__ __launch_bounds__(64)
void final_kernel(const float* __restrict__ hT,
                  const float* __restrict__ Se, const float* __restrict__ Seh,
                  const float* __restrict__ F_bw, const float* __restrict__ F_bb,
                  const float* __restrict__ Phi_w, const float* __restrict__ Phi_b,
                  float* __restrict__ out)
{
    int b = blockIdx.x;
    int tid = threadIdx.x;
    int d = tid >> 2, q = tid & 3;
    float se_inv = 1.0f / Se[(size_t)b * D_ + d];
    float mu = 0.0f, be = 0.0f;
    #pragma unroll
    for (int i = 0; i < 32; ++i) {
        int k = q * 32 + i;
        float hg = (k < 64) ? Seh[((size_t)b * D_ + d) * 64 + k] * se_inv
                            : hT[(size_t)b * DN_ + d * 64 + (k - 64)];
        mu += hg * Phi_w[k];
        be += hg * F_bw[k];
    }
    mu += __shfl_xor(mu, 1); mu += __shfl_xor(mu, 2);
    be += __shfl_xor(be, 1); be += __shfl_xor(be, 2);
    float mud = mu + Phi_b[0];
    float br  = __expf(tanhf_fast(be + F_bb[0]));
    float num = br * mud, den = br;
    #pragma unroll
    for (int off = 4; off < 64; off <<= 1) {
        num += __shfl_xor(num, off);
        den += __shfl_xor(den, off);
    }
    if (tid == 0) out[b] = num / den;
}

extern "C" void kernel_launch(void* const* d_in, const int* in_sizes, int n_in,
                              void* d_out, int out_size, void* d_ws, size_t ws_size,
                              hipStream_t stream)
{
    (void)in_sizes; (void)n_in; (void)out_size; (void)ws_size;
    const float* x     = (const float*)d_in[0];
    const float* U_j   = (const float*)d_in[1];
    const float* W_j   = (const float*)d_in[2];
    const float* b_j   = (const float*)d_in[3];
    const float* Wi_w  = (const float*)d_in[4];
    const float* Wi_b  = (const float*)d_in[5];
    const float* Wf_w  = (const float*)d_in[6];
    const float* Wf_b  = (const float*)d_in[7];
    const float* Wo_w  = (const float*)d_in[8];
    const float* Wo_b  = (const float*)d_in[9];
    const float* F_an  = (const float*)d_in[10];
    const float* F_anb = (const float*)d_in[11];
    const float* F_bw  = (const float*)d_in[12];
    const float* F_bb  = (const float*)d_in[13];
    const float* Phi_w = (const float*)d_in[14];
    const float* Phi_b = (const float*)d_in[15];
    float* out = (float*)d_out;

    char* ws = (char*)d_ws;
    unsigned short* inp0 = (unsigned short*)(ws + OFF_INP0);
    unsigned short* inp1 = (unsigned short*)(ws + OFF_INP1);
    int*   flags = (int*)(ws + OFF_FLAGS);
    float* Seh   = (float*)(ws + OFF_SEH);
    float* Se    = (float*)(ws + OFF_SE);
    float* hT    = (float*)(ws + OFF_HT);
    unsigned short* W2  = (unsigned short*)(ws + OFF_W2);
    unsigned short* Wj2 = (unsigned short*)(ws + OFF_WJ2);
    unsigned short* Wx2 = (unsigned short*)(ws + OFF_WX2);

    (void)hipMemsetAsync(d_ws, 0, ZERO_BYTES, stream);
    prep_w2<<<dim3(12288), dim3(256), 0, stream>>>(Wi_w, Wf_w, Wo_w, W2);
    prep_misc<<<dim3(640), dim3(256), 0, stream>>>(W_j, Wi_w, Wf_w, Wo_w, Wj2, Wx2);

    // 1D grid, XCD-aware decode inside the kernel; 1 block/CU (153KB LDS)
    scan_kernel<<<dim3(256), dim3(512), 0, stream>>>(
        x, U_j, b_j, Wi_b, Wf_b, Wo_b, F_an, F_anb,
        W2, Wj2, Wx2, inp0, inp1, flags, Seh, Se, hT);

    final_kernel<<<dim3(B_), dim3(64), 0, stream>>>(hT, Se, Seh, F_bw, F_bb,
                                                    Phi_w, Phi_b, out);
}